// Round 4
// baseline (633.007 us; speedup 1.0000x reference)
//
#include <hip/hip_runtime.h>
#include <math.h>

#define NB     2
#define SEQ    2048
#define NHEAD  12
#define DMODEL 768
#define SPAN2  1024
#define SCALEF 0.07216878364870323f   // 1/sqrt(192)

typedef unsigned short ushort;
typedef unsigned int   uint;
typedef __attribute__((ext_vector_type(8))) short  bh8;   // 8 x bf16
typedef __attribute__((ext_vector_type(4))) float  f32x4; // MFMA C/D frag
typedef __attribute__((ext_vector_type(4))) unsigned short us4;

__device__ inline ushort f2bf(float x) {            // RNE f32 -> bf16
    uint u = __builtin_bit_cast(uint, x);
    u += 0x7FFFu + ((u >> 16) & 1u);
    return (ushort)(u >> 16);
}
__device__ inline float b2f(ushort h) {
    uint u = ((uint)h) << 16;
    return __builtin_bit_cast(float, u);
}

// ---------------------------------------------------------------------------
// Multi-segment f32 -> bf16 convert.
// ---------------------------------------------------------------------------
struct CvtArgs {
    const float* src[8];
    ushort*      dst[8];
    int          n[8];
};

__global__ __launch_bounds__(256) void cvt_bf16(CvtArgs a)
{
    const int seg = blockIdx.y;
    const int i   = (blockIdx.x * 256 + threadIdx.x) * 8;
    if (i >= a.n[seg]) return;
    const float4* s = (const float4*)(a.src[seg] + i);
    const float4 x = s[0], y = s[1];
    bh8 o;
    o[0] = (short)f2bf(x.x); o[1] = (short)f2bf(x.y);
    o[2] = (short)f2bf(x.z); o[3] = (short)f2bf(x.w);
    o[4] = (short)f2bf(y.x); o[5] = (short)f2bf(y.y);
    o[6] = (short)f2bf(y.z); o[7] = (short)f2bf(y.w);
    *(bh8*)(a.dst[seg] + i) = o;
}

// ---------------------------------------------------------------------------
// LDS-free MFMA projection GEMM:  out = (X @ W^T + b1 + b2) * scale
// ---------------------------------------------------------------------------
__global__ __launch_bounds__(256) void proj_mfma(
    const ushort* __restrict__ X, const ushort* __restrict__ W,
    const float* __restrict__ b1, const float* __restrict__ b2,
    float scale, int rowsPerBatch,
    ushort* __restrict__ out, ushort* __restrict__ outT)
{
    const int r0 = blockIdx.x * 64;
    const int n  = blockIdx.y;
    const int c0 = n * 64;
    const int tid  = threadIdx.x;
    const int w    = tid >> 6;
    const int lane = tid & 63;
    const int lo   = lane & 15;
    const int hi8  = (lane >> 4) * 8;
    const int g4   = (lane >> 4) * 4;
    const int w16  = w * 16;

    const ushort* arow = X + (size_t)(r0 + w16 + lo) * DMODEL;

    f32x4 acc[4] = {};
    for (int k0 = 0; k0 < DMODEL; k0 += 64) {
        const bh8 a0 = *(const bh8*)&arow[k0 + hi8];
        const bh8 a1 = *(const bh8*)&arow[k0 + 32 + hi8];
        #pragma unroll
        for (int ct = 0; ct < 4; ++ct) {
            const ushort* wrow = W + (size_t)(c0 + ct * 16 + lo) * DMODEL + k0;
            const bh8 wb0 = *(const bh8*)&wrow[hi8];
            const bh8 wb1 = *(const bh8*)&wrow[32 + hi8];
            acc[ct] = __builtin_amdgcn_mfma_f32_16x16x32_bf16(a0, wb0, acc[ct], 0, 0, 0);
            acc[ct] = __builtin_amdgcn_mfma_f32_16x16x32_bf16(a1, wb1, acc[ct], 0, 0, 0);
        }
    }

    const int rbase = r0 + w16 + g4;
    const int bb  = rbase / rowsPerBatch;
    const int rr0 = rbase - bb * rowsPerBatch;
    #pragma unroll
    for (int ct = 0; ct < 4; ++ct) {
        const int d = ct * 16 + lo;
        const int c = c0 + d;
        const float badd = (b1 ? b1[c] : 0.f) + (b2 ? b2[c] : 0.f);
        if (out) {
            #pragma unroll
            for (int reg = 0; reg < 4; ++reg)
                out[(((size_t)bb * NHEAD + n) * rowsPerBatch + rr0 + reg) * 64 + d] =
                    f2bf((acc[ct][reg] + badd) * scale);
        }
        if (outT) {
            us4 o;
            #pragma unroll
            for (int reg = 0; reg < 4; ++reg)
                o[reg] = f2bf((acc[ct][reg] + badd) * scale);
            *(us4*)&outT[(((size_t)bb * NHEAD + n) * 64 + d) * rowsPerBatch + rr0] = o;
        }
    }
}

// ---------------------------------------------------------------------------
// Bias table GEMM (K=64):  C[bn][r][d] = A[bn][r][:] . B[n][d][:]
//   A: [24][2048][64] head-split (qh or kh); B: [12][1024][64] (pos proj).
//   C: [24][2048][1024] bf16.  Grid (32, 16, 24), block 256 = 4 waves.
// Epilogue via LDS so global stores are full 128B rows.
// ---------------------------------------------------------------------------
__global__ __launch_bounds__(256) void tab_gemm(
    const ushort* __restrict__ Ah, const ushort* __restrict__ Bh,
    ushort* __restrict__ Ch)
{
    __shared__ ushort Cs[64][68];
    const int bn = blockIdx.z;
    const int n  = bn % NHEAD;
    const int r0 = blockIdx.x * 64;
    const int d0 = blockIdx.y * 64;
    const int tid  = threadIdx.x;
    const int w    = tid >> 6;
    const int lane = tid & 63;
    const int lo   = lane & 15;
    const int hi8  = (lane >> 4) * 8;
    const int g4   = (lane >> 4) * 4;
    const int w16  = w * 16;

    const ushort* arow = Ah + ((size_t)bn * SEQ + r0 + w16 + lo) * 64;
    const bh8 a0 = *(const bh8*)&arow[hi8];
    const bh8 a1 = *(const bh8*)&arow[32 + hi8];

    f32x4 acc[4] = {};
    #pragma unroll
    for (int ct = 0; ct < 4; ++ct) {
        const ushort* brow = Bh + ((size_t)n * SPAN2 + d0 + ct * 16 + lo) * 64;
        const bh8 b0 = *(const bh8*)&brow[hi8];
        const bh8 b1 = *(const bh8*)&brow[32 + hi8];
        acc[ct] = __builtin_amdgcn_mfma_f32_16x16x32_bf16(a0, b0, acc[ct], 0, 0, 0);
        acc[ct] = __builtin_amdgcn_mfma_f32_16x16x32_bf16(a1, b1, acc[ct], 0, 0, 0);
    }

    #pragma unroll
    for (int ct = 0; ct < 4; ++ct)
        #pragma unroll
        for (int reg = 0; reg < 4; ++reg)
            Cs[w16 + g4 + reg][ct * 16 + lo] = f2bf(acc[ct][reg]);
    __syncthreads();

    #pragma unroll
    for (int pass = 0; pass < 2; ++pass) {
        const int row = (tid >> 3) + pass * 32;
        const int c8  = (tid & 7) * 8;
        *(bh8*)&Ch[((size_t)bn * SEQ + r0 + row) * SPAN2 + d0 + c8] =
            *(const bh8*)&Cs[row][c8];
    }
}

// ---------------------------------------------------------------------------
// MFMA flash attention v3: bias via precomputed c2p/p2c tables (per-lane
// clamped gathers), Q/K/V^T frags direct from global, P in wave-private LDS.
// ZERO barriers, zero cross-wave data.
// ---------------------------------------------------------------------------
__global__ __launch_bounds__(256) void attn_mfma3(
    const ushort* __restrict__ qh, const ushort* __restrict__ kh,
    const ushort* __restrict__ vht, const ushort* __restrict__ c2pT,
    const ushort* __restrict__ p2cT, const float* __restrict__ mask,
    float* __restrict__ attn)
{
    __shared__ ushort Ps[4][16][68];     // per-wave P tile

    const int b  = blockIdx.z;
    const int n  = blockIdx.y;
    const int i0 = blockIdx.x * 64;
    const int bn = b * NHEAD + n;
    const int tid  = threadIdx.x;
    const int w    = tid >> 6;
    const int lane = tid & 63;
    const int lo   = lane & 15;
    const int hi8  = (lane >> 4) * 8;
    const int g4   = (lane >> 4) * 4;
    const int w16  = w * 16;

    const ushort* qrow = qh + ((size_t)bn * SEQ + i0 + w16 + lo) * 64;
    const bh8 qa0 = *(const bh8*)&qrow[hi8];
    const bh8 qa1 = *(const bh8*)&qrow[32 + hi8];

    const ushort* khb = kh  + (size_t)bn * SEQ * 64;
    const ushort* vtb = vht + (size_t)bn * 64 * SEQ;
    const float*  mrw = mask + (size_t)b * SEQ;

    // chunk-invariant c2p row pointers (this wave's 4 C-frag rows)
    const ushort* c2pRow[4];
    #pragma unroll
    for (int reg = 0; reg < 4; ++reg)
        c2pRow[reg] = c2pT + ((size_t)bn * SEQ + i0 + w16 + g4 + reg) * SPAN2;
    // p2c row pointers per ct (row j0 + ct*16 + lo), advanced each chunk
    const ushort* p2cPtr[4];
    #pragma unroll
    for (int ct = 0; ct < 4; ++ct)
        p2cPtr[ct] = p2cT + ((size_t)bn * SEQ + ct * 16 + lo) * SPAN2;

    const bool gi_ok = (i0 + w16 + g4) > 0;   // reg=0 row; refined per reg below

    f32x4 accPV[4] = {};
    float mrow[4] = {-1e30f, -1e30f, -1e30f, -1e30f};
    float lrow[4] = {0.f, 0.f, 0.f, 0.f};

    for (int j0 = 0; j0 < SEQ; j0 += 64) {
        const int dconst = i0 - j0 + 512 + w16 + g4;

        // ---- bias gathers + mask (independent of MFMAs; issue first) ----
        float biasv[4][4];            // [reg][ct]
        float maskadd[4];
        #pragma unroll
        for (int ct = 0; ct < 4; ++ct) {
            const int jl = ct * 16 + lo;
            maskadd[ct] = -1e6f * (1.f - mrw[j0 + jl]);
            const bool gj_ok = (j0 + jl) > 0;
            #pragma unroll
            for (int reg = 0; reg < 4; ++reg) {
                int dlt = dconst + reg - jl;
                dlt = dlt < 0 ? 0 : (dlt > SPAN2 - 1 ? SPAN2 - 1 : dlt);
                const bool keep = (gi_ok || (i0 + w16 + g4 + reg) > 0) && gj_ok;
                biasv[reg][ct] = keep ?
                    (b2f(c2pRow[reg][dlt]) + b2f(p2cPtr[ct][dlt])) : 0.f;
            }
        }

        // ---- S = Q K^T ----
        f32x4 accS[4];
        #pragma unroll
        for (int ct = 0; ct < 4; ++ct) {
            const ushort* kr = khb + (size_t)(j0 + ct * 16 + lo) * 64;
            const bh8 kb0 = *(const bh8*)&kr[hi8];
            const bh8 kb1 = *(const bh8*)&kr[32 + hi8];
            f32x4 z = {};
            z = __builtin_amdgcn_mfma_f32_16x16x32_bf16(qa0, kb0, z, 0, 0, 0);
            accS[ct] = __builtin_amdgcn_mfma_f32_16x16x32_bf16(qa1, kb1, z, 0, 0, 0);
        }

        // ---- online softmax on C-frag layout ----
        float corr[4];
        #pragma unroll
        for (int reg = 0; reg < 4; ++reg) {
            float s[4], rmax = -1e30f;
            #pragma unroll
            for (int ct = 0; ct < 4; ++ct) {
                const float v = accS[ct][reg] + biasv[reg][ct] + maskadd[ct];
                s[ct] = v;
                rmax = fmaxf(rmax, v);
            }
            rmax = fmaxf(rmax, __shfl_xor(rmax, 1));
            rmax = fmaxf(rmax, __shfl_xor(rmax, 2));
            rmax = fmaxf(rmax, __shfl_xor(rmax, 4));
            rmax = fmaxf(rmax, __shfl_xor(rmax, 8));
            const float mnew = fmaxf(mrow[reg], rmax);
            const float cc   = __expf(mrow[reg] - mnew);
            float psum = 0.f;
            #pragma unroll
            for (int ct = 0; ct < 4; ++ct) {
                const float p = __expf(s[ct] - mnew);
                psum += p;
                Ps[w][g4 + reg][ct * 16 + lo] = f2bf(p);
            }
            psum += __shfl_xor(psum, 1);
            psum += __shfl_xor(psum, 2);
            psum += __shfl_xor(psum, 4);
            psum += __shfl_xor(psum, 8);
            lrow[reg] = lrow[reg] * cc + psum;
            mrow[reg] = mnew;
            corr[reg] = cc;
        }

        // ---- PV: A = P (wave-private LDS), B = V^T rows (global) ----
        {
            const bh8 pa0 = *(const bh8*)&Ps[w][lo][hi8];
            const bh8 pa1 = *(const bh8*)&Ps[w][lo][32 + hi8];
            #pragma unroll
            for (int dt = 0; dt < 4; ++dt) {
                const ushort* vr = vtb + (size_t)(dt * 16 + lo) * SEQ + j0;
                const bh8 vb0 = *(const bh8*)&vr[hi8];
                const bh8 vb1 = *(const bh8*)&vr[32 + hi8];
                f32x4 a = accPV[dt];
                #pragma unroll
                for (int reg = 0; reg < 4; ++reg) a[reg] *= corr[reg];
                a = __builtin_amdgcn_mfma_f32_16x16x32_bf16(pa0, vb0, a, 0, 0, 0);
                accPV[dt] = __builtin_amdgcn_mfma_f32_16x16x32_bf16(pa1, vb1, a, 0, 0, 0);
            }
        }

        #pragma unroll
        for (int ct = 0; ct < 4; ++ct) p2cPtr[ct] += (size_t)64 * SPAN2;
    }

    #pragma unroll
    for (int reg = 0; reg < 4; ++reg) {
        const int i = i0 + w16 + g4 + reg;
        const float inv = 1.f / lrow[reg];
        #pragma unroll
        for (int dt = 0; dt < 4; ++dt)
            attn[((size_t)b * SEQ + i) * DMODEL + n * 64 + dt * 16 + lo] =
                accPV[dt][reg] * inv;
    }
}

// ---------------------------------------------------------------------------
// Residual + LayerNorm, in-place on attn buffer.
// ---------------------------------------------------------------------------
__global__ __launch_bounds__(256) void resid_ln(
    float* __restrict__ attn, const float* __restrict__ query,
    const float* __restrict__ gamma, const float* __restrict__ beta)
{
    const int b = blockIdx.y;
    const int i = blockIdx.x;
    const size_t base = ((size_t)b * SEQ + i) * DMODEL;
    const int tid = threadIdx.x;

    float x[3];
    #pragma unroll
    for (int s = 0; s < 3; ++s) x[s] = attn[base + s * 256 + tid];

    float sum = x[0] + x[1] + x[2];
    float sq  = x[0]*x[0] + x[1]*x[1] + x[2]*x[2];
    #pragma unroll
    for (int off = 32; off; off >>= 1) {
        sum += __shfl_xor(sum, off);
        sq  += __shfl_xor(sq, off);
    }
    __shared__ float red[2][4];
    const int w = tid >> 6;
    if ((tid & 63) == 0) { red[0][w] = sum; red[1][w] = sq; }
    __syncthreads();
    sum = red[0][0] + red[0][1] + red[0][2] + red[0][3];
    sq  = red[1][0] + red[1][1] + red[1][2] + red[1][3];

    const float mu  = sum * (1.f / DMODEL);
    const float var = sq * (1.f / DMODEL) - mu * mu;
    const float inv = rsqrtf(var + 1e-5f);

    #pragma unroll
    for (int s = 0; s < 3; ++s) {
        const int c = s * 256 + tid;
        attn[base + c] = query[base + c] + (x[s] - mu) * inv * gamma[c] + beta[c];
    }
}

// ---------------------------------------------------------------------------
extern "C" void kernel_launch(void* const* d_in, const int* in_sizes, int n_in,
                              void* d_out, int out_size, void* d_ws, size_t ws_size,
                              hipStream_t stream)
{
    const float* query = (const float*)d_in[0];
    const float* mask  = (const float*)d_in[1];
    const float* pke   = (const float*)d_in[2];
    const float* pqe   = (const float*)d_in[3];
    const float* Wq    = (const float*)d_in[4];
    const float* bq    = (const float*)d_in[5];
    const float* Wk    = (const float*)d_in[6];
    const float* Wv    = (const float*)d_in[7];
    const float* bv    = (const float*)d_in[8];
    const float* Wpq   = (const float*)d_in[9];
    const float* bpq   = (const float*)d_in[10];
    const float* Wpk   = (const float*)d_in[11];
    const float* rwb   = (const float*)d_in[12];
    const float* gamma = (const float*)d_in[13];
    const float* beta  = (const float*)d_in[14];

    float* out = (float*)d_out;

    const int Q_N  = NB * SEQ * DMODEL;
    const int P_N  = SPAN2 * DMODEL;
    const int W_N  = DMODEL * DMODEL;
    const size_t QKV_ELEMS = (size_t)NB * NHEAD * SEQ * 64;
    const size_t POS_ELEMS = (size_t)NHEAD * SPAN2 * 64;
    const size_t TAB_ELEMS = (size_t)NB * NHEAD * SEQ * SPAN2;  // 50,331,648

    ushort* xb   = (ushort*)d_ws;
    ushort* pkeb = xb   + Q_N;
    ushort* pqeb = pkeb + P_N;
    ushort* wqb  = pqeb + P_N;
    ushort* wkb  = wqb  + W_N;
    ushort* wvb  = wkb  + W_N;
    ushort* wpqb = wvb  + W_N;
    ushort* wpkb = wpqb + W_N;
    ushort* qh   = wpkb + W_N;
    ushort* kh   = qh   + QKV_ELEMS;
    ushort* vht  = kh   + QKV_ELEMS;
    ushort* pkp  = vht  + QKV_ELEMS;
    ushort* pqp  = pkp  + POS_ELEMS;
    ushort* c2pT = pqp  + POS_ELEMS;
    ushort* p2cT = c2pT + TAB_ELEMS;

    dim3 blk(256);

    CvtArgs ca;
    ca.src[0] = query; ca.dst[0] = xb;   ca.n[0] = Q_N;
    ca.src[1] = pke;   ca.dst[1] = pkeb; ca.n[1] = P_N;
    ca.src[2] = pqe;   ca.dst[2] = pqeb; ca.n[2] = P_N;
    ca.src[3] = Wq;    ca.dst[3] = wqb;  ca.n[3] = W_N;
    ca.src[4] = Wk;    ca.dst[4] = wkb;  ca.n[4] = W_N;
    ca.src[5] = Wv;    ca.dst[5] = wvb;  ca.n[5] = W_N;
    ca.src[6] = Wpq;   ca.dst[6] = wpqb; ca.n[6] = W_N;
    ca.src[7] = Wpk;   ca.dst[7] = wpkb; ca.n[7] = W_N;
    cvt_bf16<<<dim3((Q_N / 8 + 255) / 256, 8), blk, 0, stream>>>(ca);

    proj_mfma<<<dim3(64, NHEAD), blk, 0, stream>>>(xb,   wqb,  bq,  rwb, SCALEF, SEQ,   qh,  nullptr);
    proj_mfma<<<dim3(64, NHEAD), blk, 0, stream>>>(xb,   wkb,  nullptr, nullptr, 1.f, SEQ, kh, nullptr);
    proj_mfma<<<dim3(64, NHEAD), blk, 0, stream>>>(xb,   wvb,  bv,  nullptr, 1.f,   SEQ,   nullptr, vht);
    proj_mfma<<<dim3(16, NHEAD), blk, 0, stream>>>(pkeb, wpkb, nullptr, nullptr, 1.f, SPAN2, pkp, nullptr);
    proj_mfma<<<dim3(16, NHEAD), blk, 0, stream>>>(pqeb, wpqb, bpq, nullptr, SCALEF, SPAN2, pqp, nullptr);

    // bias tables: c2p = qh . posk^T ; p2c = kh . posq_scaled^T
    tab_gemm<<<dim3(32, 16, NB * NHEAD), blk, 0, stream>>>(qh, pkp, c2pT);
    tab_gemm<<<dim3(32, 16, NB * NHEAD), blk, 0, stream>>>(kh, pqp, p2cT);

    attn_mfma3<<<dim3(SEQ / 64, NHEAD, NB), blk, 0, stream>>>(
        qh, kh, vht, c2pT, p2cT, mask, out);

    resid_ln<<<dim3(SEQ, NB), blk, 0, stream>>>(out, query, gamma, beta);
}